// Round 3
// baseline (1086.776 us; speedup 1.0000x reference)
//
#include <hip/hip_runtime.h>

#define N_NODES  100000
#define N_EDGES  3200000
#define N_FEAT   512
#define N_GRAPHS 64
#define N_COLS   516
#define NBINS    1563            // ceil(N_NODES / 64), 64 src-nodes per bin
#define NEIGH_PAD 100032         // N_NODES padded to x64
#define B1       256             // histogram column blocks
#define EPB      (N_EDGES / B1)  // 12500 edges per block chunk
#define CHUNK    25              // rows per wave in the fused x pass
#define NWAVES   (N_NODES / CHUNK)  // 4000, exact
#define DST_MASK 0x1FFFF

// ---------------------------------------------------------------------------
// K1 prep: zero out[] + 4 neigh buffers, find graph starts, per-block edge
// histogram keyed by SOURCE bin (src >> 6). grid = B1 x 1024.
// ---------------------------------------------------------------------------
__global__ __launch_bounds__(1024) void prep_kernel(
    const int* __restrict__ esrc, const int* __restrict__ gid,
    int* __restrict__ histG, int* __restrict__ starts,
    float* __restrict__ outz, float* __restrict__ neigh)
{
    __shared__ int lh[NBINS];
    const int b = blockIdx.x, tid = threadIdx.x;
    const int gtid = b * 1024 + tid;

    if (gtid < N_GRAPHS * N_COLS) outz[gtid] = 0.f;
    for (int i = gtid; i < 4 * NEIGH_PAD; i += B1 * 1024) neigh[i] = 0.f;
    if (gtid < N_NODES) {
        const int g = gid[gtid];
        const int gp = gtid ? gid[gtid - 1] : -1;
        for (int q = gp + 1; q <= g; ++q) starts[q] = gtid;
        if (gtid == N_NODES - 1)
            for (int q = g + 1; q <= N_GRAPHS; ++q) starts[q] = N_NODES;
    }
    for (int i = tid; i < NBINS; i += 1024) lh[i] = 0;
    __syncthreads();
    const int e0 = b * EPB;
    for (int e = e0 + tid; e < e0 + EPB; e += 1024)
        atomicAdd(&lh[esrc[e] >> 6], 1);
    __syncthreads();
    for (int i = tid; i < NBINS; i += 1024) histG[i * B1 + b] = lh[i];
}

// ---------------------------------------------------------------------------
// K2 fused x pass (unchanged): one read of x computes
//   p0[n]=x.Wn, s0[n]=x.Ws (wave-per-row, shuffle reduce)
//   per-graph colsum partials (registers, flushed to per-wave slots)
// ---------------------------------------------------------------------------
__device__ __forceinline__ void flush_cs(
    int si, int cur_g, const float a[8], int wave, int lane,
    float* __restrict__ pp, int* __restrict__ pt, float* __restrict__ out)
{
    if (si < 2) {
        const int slot = wave * 2 + si;
        if (lane == 0) pt[slot] = cur_g;
        float* d = pp + (size_t)slot * N_FEAT + lane * 8;
        *(float4*)d       = make_float4(a[0], a[1], a[2], a[3]);
        *(float4*)(d + 4) = make_float4(a[4], a[5], a[6], a[7]);
    } else {
        float* o = out + (size_t)cur_g * N_COLS + lane * 8;
        #pragma unroll
        for (int k = 0; k < 8; ++k) atomicAdd(o + k, a[k]);
    }
}

__global__ __launch_bounds__(256) void pass_x_kernel(
    const float* __restrict__ x, const int* __restrict__ gid,
    const float* __restrict__ wn, const float* __restrict__ ws,
    float* __restrict__ p0, float* __restrict__ s0,
    float* __restrict__ out,
    float* __restrict__ pp, int* __restrict__ pt)
{
    const int wave = (blockIdx.x * blockDim.x + threadIdx.x) >> 6;
    const int lane = threadIdx.x & 63;
    const int start = wave * CHUNK, end = start + CHUNK;   // exact fit

    const float4 wna = *(const float4*)(wn + lane * 8);
    const float4 wnb = *(const float4*)(wn + lane * 8 + 4);
    const float4 wsa = *(const float4*)(ws + lane * 8);
    const float4 wsb = *(const float4*)(ws + lane * 8 + 4);

    float a[8] = {0.f, 0.f, 0.f, 0.f, 0.f, 0.f, 0.f, 0.f};
    int cur_g = gid[start];
    const bool uniform = (gid[end - 1] == cur_g);
    int si = 0;

    for (int n = start; n < end; ++n) {
        if (!uniform) {
            const int g = gid[n];
            if (g != cur_g) {
                flush_cs(si, cur_g, a, wave, lane, pp, pt, out);
                ++si;
                #pragma unroll
                for (int k = 0; k < 8; ++k) a[k] = 0.f;
                cur_g = g;
            }
        }
        const float* row = x + (size_t)n * N_FEAT;
        const float4 xa = *(const float4*)(row + lane * 8);
        const float4 xb = *(const float4*)(row + lane * 8 + 4);

        a[0] += xa.x; a[1] += xa.y; a[2] += xa.z; a[3] += xa.w;
        a[4] += xb.x; a[5] += xb.y; a[6] += xb.z; a[7] += xb.w;

        float dn = xa.x*wna.x + xa.y*wna.y + xa.z*wna.z + xa.w*wna.w
                 + xb.x*wnb.x + xb.y*wnb.y + xb.z*wnb.z + xb.w*wnb.w;
        float dv = xa.x*wsa.x + xa.y*wsa.y + xa.z*wsa.z + xa.w*wsa.w
                 + xb.x*wsb.x + xb.y*wsb.y + xb.z*wsb.z + xb.w*wsb.w;
        #pragma unroll
        for (int off = 32; off > 0; off >>= 1) {
            dn += __shfl_down(dn, off);
            dv += __shfl_down(dv, off);
        }
        if (lane == 0) { p0[n] = dn; s0[n] = dv; }
    }
    flush_cs(si, cur_g, a, wave, lane, pp, pt, out);
    ++si;
    if (lane == 0)
        for (int s2 = si; s2 < 2; ++s2) pt[wave * 2 + s2] = -1;  // unused slots
}

// K6: fold per-wave colsum partials into out.
__global__ __launch_bounds__(512) void reduce_x_kernel(
    const float* __restrict__ pp, const int* __restrict__ pt,
    const int* __restrict__ starts, float* __restrict__ out)
{
    const int g = blockIdx.x, c = threadIdx.x;
    const int s = starts[g], e = starts[g + 1];
    float acc = 0.f;
    if (e > s) {
        const int w0 = s / CHUNK, w1 = (e - 1) / CHUNK;
        for (int w = w0; w <= w1; ++w) {
            #pragma unroll
            for (int k = 0; k < 2; ++k) {
                const int slot = w * 2 + k;
                if (pt[slot] == g) acc += pp[(size_t)slot * N_FEAT + c];
            }
        }
    }
    out[(size_t)g * N_COLS + c] += acc;
}

// ---------------------------------------------------------------------------
// Sort pipeline (counting sort by SRC bin = src >> 6).
// ---------------------------------------------------------------------------
__global__ __launch_bounds__(256) void colscan_kernel(
    const int* __restrict__ histG, int* __restrict__ colscanG,
    int* __restrict__ totalG)
{
    __shared__ int sc[256];
    const int bin = blockIdx.x, t = threadIdx.x;
    const int v = histG[bin * B1 + t];
    sc[t] = v;
    __syncthreads();
    for (int off = 1; off < 256; off <<= 1) {
        const int a = (t >= off) ? sc[t - off] : 0;
        __syncthreads();
        sc[t] += a;
        __syncthreads();
    }
    colscanG[bin * B1 + t] = sc[t] - v;
    if (t == 255) totalG[bin] = sc[255];
}

__global__ __launch_bounds__(256) void scan2_kernel(
    const int* __restrict__ totalG, int* __restrict__ binstart)
{
    __shared__ int sc[256];
    const int t = threadIdx.x;
    const int CH = 7;
    int loc[CH];
    int s = 0;
    for (int i = 0; i < CH; ++i) {
        const int bin = t * CH + i;
        const int v = (bin < NBINS) ? totalG[bin] : 0;
        loc[i] = s; s += v;
    }
    const int my = s;
    sc[t] = my;
    __syncthreads();
    for (int off = 1; off < 256; off <<= 1) {
        const int a = (t >= off) ? sc[t - off] : 0;
        __syncthreads();
        sc[t] += a;
        __syncthreads();
    }
    const int texcl = sc[t] - my;
    for (int i = 0; i < CH; ++i) {
        const int bin = t * CH + i;
        if (bin < NBINS) binstart[bin] = texcl + loc[i];
    }
    if (t == 255) binstart[NBINS] = sc[255];
}

__global__ __launch_bounds__(1024) void reorder_kernel(
    const int* __restrict__ esrc, const int* __restrict__ edst,
    const int* __restrict__ binstart, const int* __restrict__ colscanG,
    int* __restrict__ sorted)
{
    __shared__ int offs[NBINS];
    const int b = blockIdx.x, tid = threadIdx.x;
    for (int i = tid; i < NBINS; i += 1024)
        offs[i] = binstart[i] + colscanG[i * B1 + b];
    __syncthreads();
    const int e0 = b * EPB;
    for (int e = e0 + tid; e < e0 + EPB; e += 1024) {
        const int s = esrc[e], d = edst[e];
        const int p = atomicAdd(&offs[s >> 6], 1);
        sorted[p] = d | ((s & 63) << 17);      // dst[16:0] | srclow[22:17]
    }
}

// ---------------------------------------------------------------------------
// Per-layer scatter v3 (src-binned): block per 64-src bin.
// Prologue (tid<64): finish previous layer for this bin's nodes (bias + self
// + ReLU), colsum -> out[col], store h, build p = h*wnext into LDS.
// Main loop: stream bin's edges; p from LDS; fire-and-forget
// global_atomic_add into neigh_out[dst] (400 KB, L2-resident).
// Layer 0: p comes straight from p_in (x.Wn), no prologue math.
// ---------------------------------------------------------------------------
__global__ __launch_bounds__(256) void scatter_kernel(
    const int* __restrict__ sorted, const int* __restrict__ binstart,
    const float* __restrict__ neigh_in,   // null for layer 0
    const float* __restrict__ p_in,       // used when neigh_in == null
    const float* __restrict__ self_in,
    const float* __restrict__ wself_p,    // null -> 1.0
    const float* __restrict__ bias_p,
    const float* __restrict__ wnext_p,
    float* __restrict__ h_out,
    const int* __restrict__ gid, float* __restrict__ out, int col,
    float* __restrict__ neigh_out)
{
    __shared__ float ps[64];
    const int b = blockIdx.x, tid = threadIdx.x;

    if (tid < 64) {
        const int n = b * 64 + tid;
        const bool valid = (n < N_NODES);
        float p = 0.f;
        if (neigh_in) {
            float h = 0.f;
            int g = 0;
            if (valid) {
                const float sw = wself_p ? *wself_p : 1.0f;
                const float v = neigh_in[n] + *bias_p + sw * self_in[n];
                h = v > 0.f ? v : 0.f;
                h_out[n] = h;
                g = gid[n];
            }
            p = h * (*wnext_p);
            // per-graph colsum of h (this bin covers nodes [64b, 64b+64))
            const int g0 = __shfl(g, 0);
            if (__all(!valid || g == g0)) {
                float s = h;
                #pragma unroll
                for (int off = 32; off > 0; off >>= 1) s += __shfl_down(s, off);
                if (tid == 0) atomicAdd(&out[(size_t)g0 * N_COLS + col], s);
            } else if (valid) {
                atomicAdd(&out[(size_t)g * N_COLS + col], h);
            }
        } else {
            if (valid) p = p_in[n];
        }
        ps[tid] = p;
    }
    __syncthreads();

    const int st = binstart[b], en = binstart[b + 1];
    for (int e = st + tid; e < en; e += 256) {
        const int v = sorted[e];
        atomicAdd(&neigh_out[v & DST_MASK], ps[v >> 17]);
    }
}

// Final node update: h4 = relu(neigh3 + b + w*h3), colsum into col 515.
__global__ __launch_bounds__(64) void final_kernel(
    const float* __restrict__ neigh_in, const float* __restrict__ h_prev,
    const float* __restrict__ wself_p, const float* __restrict__ bias_p,
    const int* __restrict__ gid, float* __restrict__ out)
{
    const int b = blockIdx.x, tid = threadIdx.x;
    const int n = b * 64 + tid;
    const bool valid = (n < N_NODES);
    float h = 0.f;
    int g = 0;
    if (valid) {
        const float v = neigh_in[n] + *bias_p + (*wself_p) * h_prev[n];
        h = v > 0.f ? v : 0.f;
        g = gid[n];
    }
    const int g0 = __shfl(g, 0);
    if (__all(!valid || g == g0)) {
        float s = h;
        #pragma unroll
        for (int off = 32; off > 0; off >>= 1) s += __shfl_down(s, off);
        if (tid == 0) atomicAdd(&out[(size_t)g0 * N_COLS + 515], s);
    } else if (valid) {
        atomicAdd(&out[(size_t)g * N_COLS + 515], h);
    }
}

extern "C" void kernel_launch(void* const* d_in, const int* in_sizes, int n_in,
                              void* d_out, int out_size, void* d_ws, size_t ws_size,
                              hipStream_t stream)
{
    (void)in_sizes; (void)n_in; (void)out_size; (void)ws_size;

    const float* x    = (const float*)d_in[0];
    const int*   esrc = (const int*)d_in[1];
    const int*   edst = (const int*)d_in[2];
    const int*   gid  = (const int*)d_in[3];
    const float* Wn0  = (const float*)d_in[4];
    const float* Ws0  = (const float*)d_in[5];
    const float* b0p  = (const float*)d_in[6];
    const float* Wnr  = (const float*)d_in[7];
    const float* Wsr  = (const float*)d_in[8];
    const float* brp  = (const float*)d_in[9];
    float* out = (float*)d_out;

    // workspace layout (16B-aligned; all float block sizes are multiples of 4)
    float* pp    = (float*)d_ws;                         // NWAVES*2*512
    float* bufP  = pp + (size_t)NWAVES * 2 * N_FEAT;     // N_NODES
    float* bufS  = bufP + N_NODES;                       // N_NODES
    float* bufH1 = bufS + N_NODES;                       // N_NODES
    float* bufH2 = bufH1 + N_NODES;                      // N_NODES
    float* bufH3 = bufH2 + N_NODES;                      // N_NODES
    float* neigh = bufH3 + N_NODES;                      // 4 * NEIGH_PAD
    float* n0 = neigh,             *n1 = neigh + NEIGH_PAD;
    float* n2 = neigh + 2*NEIGH_PAD, *n3 = neigh + 3*NEIGH_PAD;
    int*   pt       = (int*)(neigh + 4 * NEIGH_PAD);     // NWAVES*2
    int*   starts   = pt + NWAVES * 2;                   // 65 -> pad 68
    int*   binstart = starts + 68;                       // NBINS+1 -> pad 1564
    int*   totalG   = binstart + 1564;                   // NBINS -> pad 1564
    int*   histG    = totalG + 1564;                     // NBINS*B1
    int*   colscanG = histG + (size_t)NBINS * B1;        // NBINS*B1
    int*   sorted   = colscanG + (size_t)NBINS * B1;     // N_EDGES

    prep_kernel<<<B1, 1024, 0, stream>>>(esrc, gid, histG, starts, out, neigh);
    pass_x_kernel<<<NWAVES / 4, 256, 0, stream>>>(
        x, gid, Wn0, Ws0, bufP, bufS, out, pp, pt);
    colscan_kernel<<<NBINS, 256, 0, stream>>>(histG, colscanG, totalG);
    scan2_kernel<<<1, 256, 0, stream>>>(totalG, binstart);
    reorder_kernel<<<B1, 1024, 0, stream>>>(esrc, edst, binstart, colscanG, sorted);
    reduce_x_kernel<<<N_GRAPHS, 512, 0, stream>>>(pp, pt, starts, out);

    // layer 0: p0 = x.Wn0 (bufP) -> neigh0
    scatter_kernel<<<NBINS, 256, 0, stream>>>(
        sorted, binstart, nullptr, bufP, nullptr, nullptr, nullptr, nullptr,
        nullptr, gid, out, -1, n0);
    // layer 1: h1 = relu(n0 + b0 + bufS), col 512, p1 = h1*Wnr[0] -> neigh1
    scatter_kernel<<<NBINS, 256, 0, stream>>>(
        sorted, binstart, n0, nullptr, bufS, nullptr, b0p, Wnr + 0,
        bufH1, gid, out, 512, n1);
    // layer 2: h2 = relu(n1 + br0 + Wsr0*h1), col 513, p2 = h2*Wnr[1] -> neigh2
    scatter_kernel<<<NBINS, 256, 0, stream>>>(
        sorted, binstart, n1, nullptr, bufH1, Wsr + 0, brp + 0, Wnr + 1,
        bufH2, gid, out, 513, n2);
    // layer 3: h3 = relu(n2 + br1 + Wsr1*h2), col 514, p3 = h3*Wnr[2] -> neigh3
    scatter_kernel<<<NBINS, 256, 0, stream>>>(
        sorted, binstart, n2, nullptr, bufH2, Wsr + 1, brp + 1, Wnr + 2,
        bufH3, gid, out, 514, n3);
    // final: h4 = relu(n3 + br2 + Wsr2*h3), col 515
    final_kernel<<<NBINS, 64, 0, stream>>>(n3, bufH3, Wsr + 2, brp + 2, gid, out);
}

// Round 5
// 546.596 us; speedup vs baseline: 1.9883x; 1.9883x over previous
//
#include <hip/hip_runtime.h>

#define N_NODES  100000
#define N_EDGES  3200000
#define N_FEAT   512
#define N_GRAPHS 64
#define N_COLS   516
#define B1       256             // histogram column blocks
#define EPB      (N_EDGES / B1)  // 12500 edges per block chunk
#define CHUNK    25              // rows per wave in the fused x pass
#define NWAVES   (N_NODES / CHUNK)  // 4000, exact

// 2D edge tiling: src chunks of 4096 (16 KB LDS), dst chunks of 8192 (32 KB)
#define SC_SHIFT 12
#define SC       4096
#define DC_SHIFT 13
#define DC       8192
#define NS       25              // ceil(100000/4096)
#define ND       13              // ceil(100000/8192)
#define NT       (NS * ND)       // 325 tiles
#define NPAD     (ND * DC)       // 106496 padded node slots in partials

// ---------------------------------------------------------------------------
// K1 prep: zero out[], graph starts, per-block edge histogram over NT tiles.
// 8 LDS histogram replicas to cut same-address atomic contention.
// ---------------------------------------------------------------------------
__global__ __launch_bounds__(1024) void prep_kernel(
    const int* __restrict__ esrc, const int* __restrict__ edst,
    const int* __restrict__ gid,
    int* __restrict__ histG, int* __restrict__ starts, float* __restrict__ outz)
{
    __shared__ int lh[8][NT];
    const int b = blockIdx.x, tid = threadIdx.x;
    const int gtid = b * 1024 + tid;

    if (gtid < N_GRAPHS * N_COLS) outz[gtid] = 0.f;
    if (gtid < N_NODES) {
        const int g = gid[gtid];
        const int gp = gtid ? gid[gtid - 1] : -1;
        for (int q = gp + 1; q <= g; ++q) starts[q] = gtid;
        if (gtid == N_NODES - 1)
            for (int q = g + 1; q <= N_GRAPHS; ++q) starts[q] = N_NODES;
    }
    for (int i = tid; i < 8 * NT; i += 1024) ((int*)lh)[i] = 0;
    __syncthreads();
    const int r = (tid >> 7) & 7;
    const int e0 = b * EPB;
    for (int e = e0 + tid; e < e0 + EPB; e += 1024) {
        const int t = (esrc[e] >> SC_SHIFT) * ND + (edst[e] >> DC_SHIFT);
        atomicAdd(&lh[r][t], 1);
    }
    __syncthreads();
    for (int i = tid; i < NT; i += 1024) {
        int s = 0;
        s += lh[0][i]; s += lh[1][i]; s += lh[2][i]; s += lh[3][i];
        s += lh[4][i]; s += lh[5][i]; s += lh[6][i]; s += lh[7][i];
        histG[i * B1 + b] = s;
    }
}

// ---------------------------------------------------------------------------
// K2 fused x pass: one read of x computes
//   p0[n]=x.Wn, s0[n]=x.Ws (wave-per-row, shuffle reduce)
//   per-graph colsum partials (registers, flushed to per-wave slots)
// ---------------------------------------------------------------------------
__device__ __forceinline__ void flush_cs(
    int si, int cur_g, const float a[8], int wave, int lane,
    float* __restrict__ pp, int* __restrict__ pt, float* __restrict__ out)
{
    if (si < 2) {
        const int slot = wave * 2 + si;
        if (lane == 0) pt[slot] = cur_g;
        float* d = pp + (size_t)slot * N_FEAT + lane * 8;
        *(float4*)d       = make_float4(a[0], a[1], a[2], a[3]);
        *(float4*)(d + 4) = make_float4(a[4], a[5], a[6], a[7]);
    } else {
        float* o = out + (size_t)cur_g * N_COLS + lane * 8;
        #pragma unroll
        for (int k = 0; k < 8; ++k) atomicAdd(o + k, a[k]);
    }
}

__global__ __launch_bounds__(256) void pass_x_kernel(
    const float* __restrict__ x, const int* __restrict__ gid,
    const float* __restrict__ wn, const float* __restrict__ ws,
    float* __restrict__ p0, float* __restrict__ s0,
    float* __restrict__ out,
    float* __restrict__ pp, int* __restrict__ pt)
{
    const int wave = (blockIdx.x * blockDim.x + threadIdx.x) >> 6;
    const int lane = threadIdx.x & 63;
    const int start = wave * CHUNK, end = start + CHUNK;   // exact fit

    const float4 wna = *(const float4*)(wn + lane * 8);
    const float4 wnb = *(const float4*)(wn + lane * 8 + 4);
    const float4 wsa = *(const float4*)(ws + lane * 8);
    const float4 wsb = *(const float4*)(ws + lane * 8 + 4);

    float a[8] = {0.f, 0.f, 0.f, 0.f, 0.f, 0.f, 0.f, 0.f};
    int cur_g = gid[start];
    const bool uniform = (gid[end - 1] == cur_g);
    int si = 0;

    for (int n = start; n < end; ++n) {
        if (!uniform) {
            const int g = gid[n];
            if (g != cur_g) {
                flush_cs(si, cur_g, a, wave, lane, pp, pt, out);
                ++si;
                #pragma unroll
                for (int k = 0; k < 8; ++k) a[k] = 0.f;
                cur_g = g;
            }
        }
        const float* row = x + (size_t)n * N_FEAT;
        const float4 xa = *(const float4*)(row + lane * 8);
        const float4 xb = *(const float4*)(row + lane * 8 + 4);

        a[0] += xa.x; a[1] += xa.y; a[2] += xa.z; a[3] += xa.w;
        a[4] += xb.x; a[5] += xb.y; a[6] += xb.z; a[7] += xb.w;

        float dn = xa.x*wna.x + xa.y*wna.y + xa.z*wna.z + xa.w*wna.w
                 + xb.x*wnb.x + xb.y*wnb.y + xb.z*wnb.z + xb.w*wnb.w;
        float dv = xa.x*wsa.x + xa.y*wsa.y + xa.z*wsa.z + xa.w*wsa.w
                 + xb.x*wsb.x + xb.y*wsb.y + xb.z*wsb.z + xb.w*wsb.w;
        #pragma unroll
        for (int off = 32; off > 0; off >>= 1) {
            dn += __shfl_down(dn, off);
            dv += __shfl_down(dv, off);
        }
        if (lane == 0) { p0[n] = dn; s0[n] = dv; }
    }
    flush_cs(si, cur_g, a, wave, lane, pp, pt, out);
    ++si;
    if (lane == 0)
        for (int s2 = si; s2 < 2; ++s2) pt[wave * 2 + s2] = -1;  // unused slots
}

// K6: fold per-wave colsum partials into out.
__global__ __launch_bounds__(512) void reduce_x_kernel(
    const float* __restrict__ pp, const int* __restrict__ pt,
    const int* __restrict__ starts, float* __restrict__ out)
{
    const int g = blockIdx.x, c = threadIdx.x;
    const int s = starts[g], e = starts[g + 1];
    float acc = 0.f;
    if (e > s) {
        const int w0 = s / CHUNK, w1 = (e - 1) / CHUNK;
        for (int w = w0; w <= w1; ++w) {
            #pragma unroll
            for (int k = 0; k < 2; ++k) {
                const int slot = w * 2 + k;
                if (pt[slot] == g) acc += pp[(size_t)slot * N_FEAT + c];
            }
        }
    }
    out[(size_t)g * N_COLS + c] += acc;
}

// ---------------------------------------------------------------------------
// Sort pipeline (counting sort by tile id = (src>>12)*13 + (dst>>13)).
// ---------------------------------------------------------------------------
__global__ __launch_bounds__(256) void colscan_kernel(
    const int* __restrict__ histG, int* __restrict__ colscanG,
    int* __restrict__ totalG)
{
    __shared__ int sc[256];
    const int bin = blockIdx.x, t = threadIdx.x;
    const int v = histG[bin * B1 + t];
    sc[t] = v;
    __syncthreads();
    for (int off = 1; off < 256; off <<= 1) {
        const int a = (t >= off) ? sc[t - off] : 0;
        __syncthreads();
        sc[t] += a;
        __syncthreads();
    }
    colscanG[bin * B1 + t] = sc[t] - v;
    if (t == 255) totalG[bin] = sc[255];
}

__global__ __launch_bounds__(256) void scan2_kernel(
    const int* __restrict__ totalG, int* __restrict__ binstart)
{
    __shared__ int sc[256];
    const int t = threadIdx.x;
    int loc0, loc1;
    int s = 0;
    {
        const int bin = t * 2;
        const int v0 = (bin < NT) ? totalG[bin] : 0;
        loc0 = s; s += v0;
        const int v1 = (bin + 1 < NT) ? totalG[bin + 1] : 0;
        loc1 = s; s += v1;
    }
    const int my = s;
    sc[t] = my;
    __syncthreads();
    for (int off = 1; off < 256; off <<= 1) {
        const int a = (t >= off) ? sc[t - off] : 0;
        __syncthreads();
        sc[t] += a;
        __syncthreads();
    }
    const int texcl = sc[t] - my;
    if (t * 2 < NT)     binstart[t * 2]     = texcl + loc0;
    if (t * 2 + 1 < NT) binstart[t * 2 + 1] = texcl + loc1;
    if (t == 255) binstart[NT] = sc[255];
}

__global__ __launch_bounds__(1024) void reorder_kernel(
    const int* __restrict__ esrc, const int* __restrict__ edst,
    const int* __restrict__ binstart, const int* __restrict__ colscanG,
    int* __restrict__ sorted)
{
    __shared__ int offs[NT];
    const int b = blockIdx.x, tid = threadIdx.x;
    for (int i = tid; i < NT; i += 1024)
        offs[i] = binstart[i] + colscanG[i * B1 + b];
    __syncthreads();
    const int e0 = b * EPB;
    for (int e = e0 + tid; e < e0 + EPB; e += 1024) {
        const int s = esrc[e], d = edst[e];
        const int t = (s >> SC_SHIFT) * ND + (d >> DC_SHIFT);
        const int p = atomicAdd(&offs[t], 1);
        sorted[p] = ((s & (SC - 1)) << DC_SHIFT) | (d & (DC - 1));
    }
}

// ---------------------------------------------------------------------------
// Tile scatter: block per tile (s,d). Stage src-chunk p into LDS, accumulate
// into LDS dst-chunk acc (ds_atomic), write acc as coalesced plain stores to
// partial[s][d*DC .. ) — disjoint per block, zero global atomics, zero
// per-edge random global access.
// ---------------------------------------------------------------------------
__global__ __launch_bounds__(1024) void tile_scatter_kernel(
    const int* __restrict__ sorted, const int* __restrict__ tilestart,
    const float* __restrict__ ps_global, float* __restrict__ partial)
{
    __shared__ float ps[SC];
    __shared__ float acc[DC];
    const int t = blockIdx.x, tid = threadIdx.x;
    const int s = t / ND, d = t - s * ND;

    const int nbase = s << SC_SHIFT;
    for (int i = tid; i < SC; i += 1024) {
        const int n = nbase + i;
        ps[i] = (n < N_NODES) ? ps_global[n] : 0.f;
    }
    for (int i = tid; i < DC; i += 1024) acc[i] = 0.f;
    __syncthreads();

    const int st = tilestart[t], en = tilestart[t + 1];
    for (int e = st + tid; e < en; e += 1024) {
        const int v = sorted[e];
        atomicAdd(&acc[v & (DC - 1)], ps[v >> DC_SHIFT]);
    }
    __syncthreads();

    float* dst = partial + (size_t)s * NPAD + ((size_t)d << DC_SHIFT);
    for (int i = tid; i < DC; i += 1024) dst[i] = acc[i];
}

// ---------------------------------------------------------------------------
// Fused reduce + node update: neigh[n] = sum_s partial[s][n]; h = relu(neigh
// + bias + wself*self); per-graph colsum -> out[col]; store h and next p.
// ---------------------------------------------------------------------------
__global__ __launch_bounds__(256) void reduce_update_kernel(
    const float* __restrict__ partial, const float* __restrict__ self_in,
    const float* __restrict__ wself_p,    // null -> 1.0
    const float* __restrict__ bias_p,
    const float* __restrict__ wnext_p,    // null -> no p_next write
    float* __restrict__ h_out, float* __restrict__ p_next,
    const int* __restrict__ gid, float* __restrict__ out, int col)
{
    const int n = blockIdx.x * 256 + threadIdx.x;
    const bool valid = (n < N_NODES);
    float h = 0.f;
    int g = 0;
    if (valid) {
        float nb = 0.f;
        #pragma unroll
        for (int s = 0; s < NS; ++s) nb += partial[(size_t)s * NPAD + n];
        const float sw = wself_p ? *wself_p : 1.0f;
        const float v = nb + *bias_p + sw * self_in[n];
        h = v > 0.f ? v : 0.f;
        h_out[n] = h;
        if (wnext_p) p_next[n] = h * (*wnext_p);
        g = gid[n];
    }
    const int g0 = __shfl(g, 0);
    if (__all(!valid || g == g0)) {
        float sv = h;
        #pragma unroll
        for (int off = 32; off > 0; off >>= 1) sv += __shfl_down(sv, off);
        if ((threadIdx.x & 63) == 0) atomicAdd(&out[(size_t)g0 * N_COLS + col], sv);
    } else if (valid) {
        atomicAdd(&out[(size_t)g * N_COLS + col], h);
    }
}

extern "C" void kernel_launch(void* const* d_in, const int* in_sizes, int n_in,
                              void* d_out, int out_size, void* d_ws, size_t ws_size,
                              hipStream_t stream)
{
    (void)in_sizes; (void)n_in; (void)out_size; (void)ws_size;

    const float* x    = (const float*)d_in[0];
    const int*   esrc = (const int*)d_in[1];
    const int*   edst = (const int*)d_in[2];
    const int*   gid  = (const int*)d_in[3];
    const float* Wn0  = (const float*)d_in[4];
    const float* Ws0  = (const float*)d_in[5];
    const float* b0p  = (const float*)d_in[6];
    const float* Wnr  = (const float*)d_in[7];
    const float* Wsr  = (const float*)d_in[8];
    const float* brp  = (const float*)d_in[9];
    float* out = (float*)d_out;

    // workspace layout (16B-aligned; float block sizes are multiples of 4)
    float* pp      = (float*)d_ws;                       // NWAVES*2*512
    float* bufP    = pp + (size_t)NWAVES * 2 * N_FEAT;   // N_NODES
    float* bufS    = bufP + N_NODES;                     // N_NODES (x.Ws)
    float* bufH1   = bufS + N_NODES;                     // N_NODES
    float* bufH2   = bufH1 + N_NODES;                    // N_NODES
    float* bufPn   = bufH2 + N_NODES;                    // N_NODES
    float* partial = bufPn + N_NODES;                    // NS * NPAD
    int*   pt       = (int*)(partial + (size_t)NS * NPAD); // NWAVES*2
    int*   starts   = pt + NWAVES * 2;                   // 65 -> pad 68
    int*   binstart = starts + 68;                       // NT+1 -> pad 328
    int*   totalG   = binstart + 328;                    // NT -> pad 328
    int*   histG    = totalG + 328;                      // NT*B1
    int*   colscanG = histG + (size_t)NT * B1;           // NT*B1
    int*   sorted   = colscanG + (size_t)NT * B1;        // N_EDGES

    prep_kernel<<<B1, 1024, 0, stream>>>(esrc, edst, gid, histG, starts, out);
    pass_x_kernel<<<NWAVES / 4, 256, 0, stream>>>(
        x, gid, Wn0, Ws0, bufP, bufS, out, pp, pt);
    colscan_kernel<<<NT, 256, 0, stream>>>(histG, colscanG, totalG);
    scan2_kernel<<<1, 256, 0, stream>>>(totalG, binstart);
    reorder_kernel<<<B1, 1024, 0, stream>>>(esrc, edst, binstart, colscanG, sorted);
    reduce_x_kernel<<<N_GRAPHS, 512, 0, stream>>>(pp, pt, starts, out);

    const int RB = (N_NODES + 255) / 256;   // 391

    // conv0: p0 = x.Wn0 (bufP); h1 = relu(neigh + b0 + x.Ws0); col 512
    tile_scatter_kernel<<<NT, 1024, 0, stream>>>(sorted, binstart, bufP, partial);
    reduce_update_kernel<<<RB, 256, 0, stream>>>(
        partial, bufS, nullptr, b0p, Wnr + 0, bufH1, bufPn, gid, out, 512);
    // conv1: h2 = relu(neigh + br0 + Wsr0*h1); col 513
    tile_scatter_kernel<<<NT, 1024, 0, stream>>>(sorted, binstart, bufPn, partial);
    reduce_update_kernel<<<RB, 256, 0, stream>>>(
        partial, bufH1, Wsr + 0, brp + 0, Wnr + 1, bufH2, bufPn, gid, out, 513);
    // conv2: h3 = relu(neigh + br1 + Wsr1*h2); col 514
    tile_scatter_kernel<<<NT, 1024, 0, stream>>>(sorted, binstart, bufPn, partial);
    reduce_update_kernel<<<RB, 256, 0, stream>>>(
        partial, bufH2, Wsr + 1, brp + 1, Wnr + 2, bufH1, bufPn, gid, out, 514);
    // conv3: h4 = relu(neigh + br2 + Wsr2*h3); col 515 (no p_next)
    tile_scatter_kernel<<<NT, 1024, 0, stream>>>(sorted, binstart, bufPn, partial);
    reduce_update_kernel<<<RB, 256, 0, stream>>>(
        partial, bufH1, Wsr + 2, brp + 2, nullptr, bufH2, nullptr, gid, out, 515);
}